// Round 2
// baseline (701.305 us; speedup 1.0000x reference)
//
#include <hip/hip_runtime.h>
#include <math.h>

#define ND 128
#define ED 64
#define LN_EPS 1e-5f
#define TE 32        // edges per block (edge kernel)
#define SXH 328      // edge LDS row stride (halves): 656B/row; as float stride = 164 dw
#define GSH 136      // gru f16 LDS row stride (halves)
#define GSF 132      // gru fp32 LDS row stride (floats)

typedef _Float16 f16;
typedef __attribute__((ext_vector_type(8))) _Float16 f16x8;
typedef __attribute__((ext_vector_type(4))) _Float16 f16x4;
typedef __attribute__((ext_vector_type(4))) float f32x4;

// async global->LDS DMA: per-lane global addr, wave-uniform LDS base (+lane*4 by HW)
#define GLD4(gp, lp) __builtin_amdgcn_global_load_lds( \
    (const __attribute__((address_space(1))) void*)(gp), \
    (__attribute__((address_space(3))) void*)(lp), 4, 0, 0)

__device__ __forceinline__ float sigmoidf_(float x) { return 1.f / (1.f + expf(-x)); }

// ---- weight conversion fp32 -> f16 (+transpose for W1,W2), fused with nf->f16 ----
// W1f[n*320+k] = W1[k*128+n]; W2f[n*128+k] = W2[k*128+n]; Wih/Whh straight.
__global__ void convert_kernel(const float* __restrict__ W1, const float* __restrict__ W2,
                               const float* __restrict__ Wih, const float* __restrict__ Whh,
                               const float* __restrict__ nf,
                               f16* __restrict__ W1f, f16* __restrict__ W2f,
                               f16* __restrict__ Wihf, f16* __restrict__ Whhf,
                               f16* __restrict__ nf16, int n8)
{
    int idx = blockIdx.x * 256 + threadIdx.x;
    if (idx < 40960) {
        int n = idx / 320, k = idx - n * 320;
        W1f[idx] = (f16)W1[k * 128 + n];
    } else if (idx < 57344) {
        int i2 = idx - 40960; int n = i2 >> 7, k = i2 & 127;
        W2f[i2] = (f16)W2[k * 128 + n];
    } else if (idx < 106496) {
        int i3 = idx - 57344;  Wihf[i3] = (f16)Wih[i3];
    } else if (idx < 155648) {
        int i4 = idx - 106496; Whhf[i4] = (f16)Whh[i4];
    } else {
        int i5 = idx - 155648;
        if (i5 < n8) {
            float4 a = ((const float4*)nf)[2 * i5];
            float4 b = ((const float4*)nf)[2 * i5 + 1];
            f16x8 h;
            h[0] = (f16)a.x; h[1] = (f16)a.y; h[2] = (f16)a.z; h[3] = (f16)a.w;
            h[4] = (f16)b.x; h[5] = (f16)b.y; h[6] = (f16)b.z; h[7] = (f16)b.w;
            ((f16x8*)nf16)[i5] = h;
        }
    }
}

// ---- CSR-style dst-sort: histogram -> scan -> scatter-rank ----
__global__ void hist_kernel(const int* __restrict__ eidx, int* __restrict__ cnt, int E) {
    int i = blockIdx.x * 256 + threadIdx.x;
    if (i < E) atomicAdd(&cnt[eidx[E + i]], 1);
}

__global__ __launch_bounds__(1024)
void scan_kernel(const int* __restrict__ cnt, int* __restrict__ woff, int N) {
    __shared__ int part[1024];
    const int t = threadIdx.x;
    const int CH = 40;
    int base = t * CH;
    int s = 0;
    for (int i = 0; i < CH; ++i) { int idx = base + i; if (idx < N) s += cnt[idx]; }
    part[t] = s;
    __syncthreads();
    for (int d = 1; d < 1024; d <<= 1) {
        int v = (t >= d) ? part[t - d] : 0;
        __syncthreads();
        part[t] += v;
        __syncthreads();
    }
    int run = (t == 0) ? 0 : part[t - 1];
    for (int i = 0; i < CH; ++i) {
        int idx = base + i;
        if (idx < N) { woff[idx] = run; run += cnt[idx]; }
    }
}

__global__ void scatter_kernel(const int* __restrict__ eidx, int* __restrict__ woff,
                               int* __restrict__ perm, int E) {
    int i = blockIdx.x * 256 + threadIdx.x;
    if (i < E) {
        int p = atomicAdd(&woff[eidx[E + i]], 1);
        perm[p] = i;
    }
}

// ---------------- edge message kernel (f16 MFMA, N-partitioned waves) ----------------
// 256 thr = 4 waves; 32 dst-sorted edges/block (23 KB LDS -> 6 blocks/CU).
// Wave w owns cols [32w,32w+32) (2 N-tiles) over ALL 32 edges (2 M-tiles).
// src/dst rows staged by global_load_lds DMA; edge ids held in lanes<32 of every wave.
__global__ __launch_bounds__(256, 5)
void edge_kernel(const f16* __restrict__ nf16, const int* __restrict__ eidx,
                 const float* __restrict__ ef, const int* __restrict__ perm,
                 const f16* __restrict__ W1f, const float* __restrict__ b1,
                 const float* __restrict__ ln_g, const float* __restrict__ ln_b,
                 const f16* __restrict__ W2f, const float* __restrict__ b2,
                 const float* __restrict__ gate_w, const float* __restrict__ gate_b,
                 float* __restrict__ agg, int E)
{
    __shared__ f16   sxh[TE * SXH];       // 21 KB: x tile f16; reused for h' then fp32 messages
    __shared__ float sred[TE * 8];        // LN partials [row][w*2 + {p1,p2}]
    __shared__ float spart[TE][8];        // gate partials
    __shared__ float sg[TE];              // per-edge gate

    const int tid  = threadIdx.x;
    const int lane = tid & 63;
    const int w    = __builtin_amdgcn_readfirstlane(tid >> 6);
    const int cb   = 32 * w;              // column base for this wave
    const int c    = lane & 15;
    const int quad = lane >> 4;
    const int e0   = blockIdx.x * TE;

    // every wave: lanes 0..31 fetch edge id + src/dst (no LDS, no barrier)
    int ev = 0, sr = 0, dr = 0;
    if (lane < 32) {
        ev = perm[e0 + lane];
        sr = eidx[ev];
        dr = eidx[E + ev];
    }

    // ---- DMA src/dst rows into LDS: wave w covers rows [8w, 8w+8) ----
    #pragma unroll
    for (int i = 0; i < 8; ++i) {
        int r = 8 * w + i;
        int srcr = __builtin_amdgcn_readlane(sr, r);
        int drr  = __builtin_amdgcn_readlane(dr, r);
        GLD4(nf16 + (size_t)srcr * ND + 2 * lane, sxh + r * SXH);         // cols [0,128)
        GLD4(nf16 + (size_t)drr  * ND + 2 * lane, sxh + r * SXH + 128);   // cols [128,256)
    }

    // ---- ef stage (fp32->f16, cols [256,320)) + gate partial: 8 threads/row ----
    {
        const int r = tid >> 3, q = tid & 7;     // r == 8w + (lane>>3)
        int er = __shfl(ev, r);                  // edge id for this row (from lane r < 32)
        const float* erow = ef + (size_t)er * ED + q * 8;
        float4 v0 = *(const float4*)erow;
        float4 v1 = *(const float4*)(erow + 4);
        f16x4 h0; h0[0] = (f16)v0.x; h0[1] = (f16)v0.y; h0[2] = (f16)v0.z; h0[3] = (f16)v0.w;
        f16x4 h1; h1[0] = (f16)v1.x; h1[1] = (f16)v1.y; h1[2] = (f16)v1.z; h1[3] = (f16)v1.w;
        f16* dp = sxh + r * SXH + 256 + q * 8;
        *(f16x4*)dp = h0;
        *(f16x4*)(dp + 4) = h1;
        const float* gw = gate_w + q * 8;
        float gp = 0.f;
        gp = fmaf(v0.x, gw[0], gp); gp = fmaf(v0.y, gw[1], gp);
        gp = fmaf(v0.z, gw[2], gp); gp = fmaf(v0.w, gw[3], gp);
        gp = fmaf(v1.x, gw[4], gp); gp = fmaf(v1.y, gw[5], gp);
        gp = fmaf(v1.z, gw[6], gp); gp = fmaf(v1.w, gw[7], gp);
        spart[r][q] = gp;
    }
    __syncthreads();   // B1: drains DMA (vmcnt) + LDS writes

    if (tid < TE) {    // sg consumed after B5; B3 gives visibility
        float s = spart[tid][0] + spart[tid][1] + spart[tid][2] + spart[tid][3]
                + spart[tid][4] + spart[tid][5] + spart[tid][6] + spart[tid][7];
        sg[tid] = sigmoidf_(s + gate_b[0]);
    }

    // ---- GEMM1: [32x320] @ [320x(32 cols/wave)] ----
    f32x4 acc[2][2];
    #pragma unroll
    for (int mt = 0; mt < 2; ++mt)
        #pragma unroll
        for (int nt = 0; nt < 2; ++nt) acc[mt][nt] = (f32x4){0.f, 0.f, 0.f, 0.f};

    #pragma unroll
    for (int ks = 0; ks < 10; ++ks) {
        f16x8 b0 = *(const f16x8*)(W1f + (cb + c) * 320 + ks * 32 + quad * 8);
        f16x8 b1v = *(const f16x8*)(W1f + (cb + 16 + c) * 320 + ks * 32 + quad * 8);
        #pragma unroll
        for (int mt = 0; mt < 2; ++mt) {
            f16x8 a = *(const f16x8*)(sxh + (16 * mt + c) * SXH + ks * 32 + quad * 8);
            acc[mt][0] = __builtin_amdgcn_mfma_f32_16x16x32_f16(a, b0,  acc[mt][0], 0, 0, 0);
            acc[mt][1] = __builtin_amdgcn_mfma_f32_16x16x32_f16(a, b1v, acc[mt][1], 0, 0, 0);
        }
    }

    // ---- bias + LN partials over this wave's 32 cols ----
    float b1c[2], gvc[2], bvc[2], b2c[2];
    #pragma unroll
    for (int nt = 0; nt < 2; ++nt) {
        int col = cb + nt * 16 + c;
        b1c[nt] = b1[col]; gvc[nt] = ln_g[col]; bvc[nt] = ln_b[col]; b2c[nt] = b2[col];
    }
    #pragma unroll
    for (int mt = 0; mt < 2; ++mt) {
        float p1[4] = {0, 0, 0, 0}, p2[4] = {0, 0, 0, 0};
        #pragma unroll
        for (int nt = 0; nt < 2; ++nt)
            #pragma unroll
            for (int r = 0; r < 4; ++r) {
                float vv = acc[mt][nt][r] + b1c[nt];
                acc[mt][nt][r] = vv;
                p1[r] += vv; p2[r] += vv * vv;
            }
        #pragma unroll
        for (int m = 1; m < 16; m <<= 1)
            #pragma unroll
            for (int r = 0; r < 4; ++r) {
                p1[r] += __shfl_xor(p1[r], m);
                p2[r] += __shfl_xor(p2[r], m);
            }
        if (c == 0) {
            #pragma unroll
            for (int r = 0; r < 4; ++r) {
                int row = 16 * mt + 4 * quad + r;
                sred[row * 8 + 2 * w + 0] = p1[r];
                sred[row * 8 + 2 * w + 1] = p2[r];
            }
        }
    }
    __syncthreads();   // B3

    // ---- LN finalize + ReLU; h' (f16) into cols [0,128) ----
    #pragma unroll
    for (int mt = 0; mt < 2; ++mt)
        #pragma unroll
        for (int r = 0; r < 4; ++r) {
            int row = 16 * mt + 4 * quad + r;
            f32x4 lo = *(const f32x4*)(sred + row * 8);
            f32x4 hi = *(const f32x4*)(sred + row * 8 + 4);
            float t1 = lo[0] + lo[2] + hi[0] + hi[2];
            float t2 = lo[1] + lo[3] + hi[1] + hi[3];
            float mu = t1 * (1.f / 128.f);
            float var = t2 * (1.f / 128.f) - mu * mu;
            float rs = rsqrtf(var + LN_EPS);
            #pragma unroll
            for (int nt = 0; nt < 2; ++nt) {
                float vv = (acc[mt][nt][r] - mu) * rs * gvc[nt] + bvc[nt];
                vv = vv > 0.f ? vv : 0.f;
                sxh[row * SXH + cb + nt * 16 + c] = (f16)vv;
            }
        }
    __syncthreads();   // B4

    // ---- GEMM2: [32x128] @ [128x(32 cols/wave)] ----
    f32x4 acc2[2][2];
    #pragma unroll
    for (int mt = 0; mt < 2; ++mt)
        #pragma unroll
        for (int nt = 0; nt < 2; ++nt) acc2[mt][nt] = (f32x4){0.f, 0.f, 0.f, 0.f};
    #pragma unroll
    for (int ks = 0; ks < 4; ++ks) {
        f16x8 b0 = *(const f16x8*)(W2f + (cb + c) * 128 + ks * 32 + quad * 8);
        f16x8 b1v = *(const f16x8*)(W2f + (cb + 16 + c) * 128 + ks * 32 + quad * 8);
        #pragma unroll
        for (int mt = 0; mt < 2; ++mt) {
            f16x8 a = *(const f16x8*)(sxh + (16 * mt + c) * SXH + ks * 32 + quad * 8);
            acc2[mt][0] = __builtin_amdgcn_mfma_f32_16x16x32_f16(a, b0,  acc2[mt][0], 0, 0, 0);
            acc2[mt][1] = __builtin_amdgcn_mfma_f32_16x16x32_f16(a, b1v, acc2[mt][1], 0, 0, 0);
        }
    }
    __syncthreads();   // B5: all h' reads done -> safe to overwrite tile with fp32 messages

    // ---- gated messages (fp32) into LDS ----
    float* smsg = (float*)sxh;   // stride 164 dw per row
    #pragma unroll
    for (int mt = 0; mt < 2; ++mt)
        #pragma unroll
        for (int r = 0; r < 4; ++r) {
            int row = 16 * mt + 4 * quad + r;
            float gr = sg[row];
            #pragma unroll
            for (int nt = 0; nt < 2; ++nt)
                smsg[row * 164 + cb + nt * 16 + c] = (acc2[mt][nt][r] + b2c[nt]) * gr;
        }
    __syncthreads();   // B6

    // ---- segment reduction over sorted dst: wave w walks rows [8w,8w+8), 2 cols/lane ----
    {
        const int rbase = 8 * w;
        const float* sm = smsg + rbase * 164;
        float run0 = sm[lane];
        float run1 = sm[64 + lane];
        int prev = __builtin_amdgcn_readlane(dr, rbase);
        #pragma unroll
        for (int r = 1; r < 8; ++r) {
            int d = __builtin_amdgcn_readlane(dr, rbase + r);
            float v0 = sm[r * 164 + lane];
            float v1 = sm[r * 164 + 64 + lane];
            if (d == prev) { run0 += v0; run1 += v1; }
            else {
                atomicAdd(agg + (size_t)prev * ND + lane,      run0);
                atomicAdd(agg + (size_t)prev * ND + 64 + lane, run1);
                run0 = v0; run1 = v1; prev = d;
            }
        }
        atomicAdd(agg + (size_t)prev * ND + lane,      run0);
        atomicAdd(agg + (size_t)prev * ND + 64 + lane, run1);
    }
}

// ---------------- GRU kernel (f16 MFMA) ----------------
// 256 thr = 4 waves; 32 nodes/block. Wave w owns gate-cols [32w,32w+32).
__global__ __launch_bounds__(256, 2)
void gru_kernel(const float* __restrict__ agg, const float* __restrict__ nf,
                const f16* __restrict__ Wihf, const float* __restrict__ b_ih,
                const f16* __restrict__ Whhf, const float* __restrict__ b_hh,
                float* __restrict__ out)
{
    __shared__ f16   sa[32 * GSH];
    __shared__ f16   sh[32 * GSH];
    __shared__ float shf[32 * GSF];   // fp32 h_prev for the z*h term

    const int tid  = threadIdx.x;
    const int lane = tid & 63;
    const int w    = __builtin_amdgcn_readfirstlane(tid >> 6);
    const int c    = lane & 15;
    const int quad = lane >> 4;
    const int n0   = blockIdx.x * 32;

    {
        const int r = tid >> 3, q = tid & 7;
        const float* arow = agg + (size_t)(n0 + r) * ND;
        const float* hrow = nf  + (size_t)(n0 + r) * ND;
        #pragma unroll
        for (int i = 0; i < 4; ++i) {
            int ec = (q + 8 * i) * 4;
            float4 va = *(const float4*)(arow + ec);
            f16x4 ha; ha[0] = (f16)va.x; ha[1] = (f16)va.y; ha[2] = (f16)va.z; ha[3] = (f16)va.w;
            *(f16x4*)(sa + r * GSH + ec) = ha;
            float4 vh = *(const float4*)(hrow + ec);
            f16x4 hh; hh[0] = (f16)vh.x; hh[1] = (f16)vh.y; hh[2] = (f16)vh.z; hh[3] = (f16)vh.w;
            *(f16x4*)(sh + r * GSH + ec) = hh;
            *(float4*)(shf + r * GSF + ec) = vh;
        }
    }
    __syncthreads();

    f32x4 aI[2][6], aH[2][6];   // [mt][gg*2+nt]
    #pragma unroll
    for (int mt = 0; mt < 2; ++mt)
        #pragma unroll
        for (int j = 0; j < 6; ++j) {
            aI[mt][j] = (f32x4){0.f, 0.f, 0.f, 0.f};
            aH[mt][j] = (f32x4){0.f, 0.f, 0.f, 0.f};
        }

    #pragma unroll
    for (int ks = 0; ks < 4; ++ks) {
        f16x8 fa[2], fh[2];
        #pragma unroll
        for (int mt = 0; mt < 2; ++mt) {
            fa[mt] = *(const f16x8*)(sa + (16 * mt + c) * GSH + ks * 32 + quad * 8);
            fh[mt] = *(const f16x8*)(sh + (16 * mt + c) * GSH + ks * 32 + quad * 8);
        }
        #pragma unroll
        for (int gg = 0; gg < 3; ++gg)
            #pragma unroll
            for (int nt = 0; nt < 2; ++nt) {
                int coln = gg * 128 + 32 * w + nt * 16 + c;
                f16x8 bI = *(const f16x8*)(Wihf + coln * 128 + ks * 32 + quad * 8);
                f16x8 bH = *(const f16x8*)(Whhf + coln * 128 + ks * 32 + quad * 8);
                #pragma unroll
                for (int mt = 0; mt < 2; ++mt) {
                    int j = gg * 2 + nt;
                    aI[mt][j] = __builtin_amdgcn_mfma_f32_16x16x32_f16(fa[mt], bI, aI[mt][j], 0, 0, 0);
                    aH[mt][j] = __builtin_amdgcn_mfma_f32_16x16x32_f16(fh[mt], bH, aH[mt][j], 0, 0, 0);
                }
            }
    }

    #pragma unroll
    for (int nt = 0; nt < 2; ++nt) {
        int col = 32 * w + nt * 16 + c;
        float bir = b_ih[col], biz = b_ih[128 + col], bin = b_ih[256 + col];
        float bhr = b_hh[col], bhz = b_hh[128 + col], bhn = b_hh[256 + col];
        #pragma unroll
        for (int mt = 0; mt < 2; ++mt)
            #pragma unroll
            for (int r = 0; r < 4; ++r) {
                int row = 16 * mt + 4 * quad + r;
                float rr = sigmoidf_(aI[mt][0 + nt][r] + bir + aH[mt][0 + nt][r] + bhr);
                float zz = sigmoidf_(aI[mt][2 + nt][r] + biz + aH[mt][2 + nt][r] + bhz);
                float nn = tanhf(aI[mt][4 + nt][r] + bin + rr * (aH[mt][4 + nt][r] + bhn));
                float hp = shf[row * GSF + col];
                out[(size_t)(n0 + row) * ND + col] = (1.f - zz) * nn + zz * hp;
            }
    }
}

extern "C" void kernel_launch(void* const* d_in, const int* in_sizes, int n_in,
                              void* d_out, int out_size, void* d_ws, size_t ws_size,
                              hipStream_t stream) {
    const float* nf     = (const float*)d_in[0];
    const int*   eidx   = (const int*)  d_in[1];
    const float* ef     = (const float*)d_in[2];
    const float* W1     = (const float*)d_in[3];
    const float* b1     = (const float*)d_in[4];
    const float* ln_g   = (const float*)d_in[5];
    const float* ln_b   = (const float*)d_in[6];
    const float* W2     = (const float*)d_in[7];
    const float* b2     = (const float*)d_in[8];
    const float* gate_w = (const float*)d_in[9];
    const float* gate_b = (const float*)d_in[10];
    const float* W_ih   = (const float*)d_in[11];
    const float* b_ih   = (const float*)d_in[12];
    const float* W_hh   = (const float*)d_in[13];
    const float* b_hh   = (const float*)d_in[14];
    float* out = (float*)d_out;

    const int N = in_sizes[0] / ND;   // 40000
    const int E = in_sizes[1] / 2;    // 640000

    char* ws = (char*)d_ws;
    float* agg = (float*)ws;          ws += (size_t)N * ND * 4;   // 20.48 MB
    f16* nf16 = (f16*)ws;             ws += (size_t)N * ND * 2;   // 10.24 MB
    f16* W1f  = (f16*)ws;             ws += 40960 * 2;
    f16* W2f  = (f16*)ws;             ws += 16384 * 2;
    f16* Wihf = (f16*)ws;             ws += 49152 * 2;
    f16* Whhf = (f16*)ws;             ws += 49152 * 2;
    int* cnt  = (int*)ws;             ws += 40960 * 4;
    int* woff = (int*)ws;             ws += 40960 * 4;
    int* perm = (int*)ws;             ws += (size_t)E * 4;        // 2.56 MB

    hipMemsetAsync(agg, 0, (size_t)N * ND * 4, stream);
    hipMemsetAsync(cnt, 0, (size_t)N * 4, stream);
    const int n8 = N * ND / 8;        // 640000 8-float chunks
    const int cvt_items = 155648 + n8;
    convert_kernel<<<(cvt_items + 255) / 256, 256, 0, stream>>>(
        W1, W2, W_ih, W_hh, nf, W1f, W2f, Wihf, Whhf, nf16, n8);
    hist_kernel<<<(E + 255) / 256, 256, 0, stream>>>(eidx, cnt, E);
    scan_kernel<<<1, 1024, 0, stream>>>(cnt, woff, N);
    scatter_kernel<<<(E + 255) / 256, 256, 0, stream>>>(eidx, woff, perm, E);
    edge_kernel<<<E / TE, 256, 0, stream>>>(nf16, eidx, ef, perm, W1f, b1, ln_g, ln_b,
                                            W2f, b2, gate_w, gate_b, agg, E);
    gru_kernel<<<N / 32, 256, 0, stream>>>(agg, nf, Wihf, b_ih, Whhf, b_hh, out);
}

// Round 3
// 562.134 us; speedup vs baseline: 1.2476x; 1.2476x over previous
//
#include <hip/hip_runtime.h>
#include <math.h>

#define ND 128
#define ED 64
#define LN_EPS 1e-5f
#define TE 64        // edges per block (edge kernel)
#define GSH 136      // gru/h12 f16 LDS row stride (halves)
#define GSF 132      // gru fp32 LDS row stride (floats)

typedef _Float16 f16;
typedef __attribute__((ext_vector_type(8))) _Float16 f16x8;
typedef __attribute__((ext_vector_type(4))) _Float16 f16x4;
typedef __attribute__((ext_vector_type(4))) float f32x4;

__device__ __forceinline__ float sigmoidf_(float x) { return 1.f / (1.f + expf(-x)); }

// ---- weight conversion fp32 -> f16 ----
// Wcatf[c*128+k] = c<128 ? W1[k][c] : W1[128+k][c-128]   (32768, for H12 GEMM)
// W1ef[n*64+k]   = W1[256+k][n]                          (8192,  edge GEMM1e)
// W2f[n*128+k]   = W2[k][n]                              (16384)
// Wihf/Whhf straight copies (49152 each). Total 155648 items.
__global__ void convert_kernel(const float* __restrict__ W1, const float* __restrict__ W2,
                               const float* __restrict__ Wih, const float* __restrict__ Whh,
                               f16* __restrict__ Wcatf, f16* __restrict__ W1ef,
                               f16* __restrict__ W2f,
                               f16* __restrict__ Wihf, f16* __restrict__ Whhf)
{
    int idx = blockIdx.x * 256 + threadIdx.x;
    if (idx < 32768) {
        int cc = idx >> 7, k = idx & 127;
        Wcatf[idx] = (f16)(cc < 128 ? W1[k * 128 + cc] : W1[(128 + k) * 128 + (cc - 128)]);
    } else if (idx < 40960) {
        int i2 = idx - 32768; int n = i2 >> 6, k = i2 & 63;
        W1ef[i2] = (f16)W1[(256 + k) * 128 + n];
    } else if (idx < 57344) {
        int i3 = idx - 40960; int n = i3 >> 7, k = i3 & 127;
        W2f[i3] = (f16)W2[k * 128 + n];
    } else if (idx < 106496) {
        int i4 = idx - 57344;  Wihf[i4] = (f16)Wih[i4];
    } else if (idx < 155648) {
        int i5 = idx - 106496; Whhf[i5] = (f16)Whh[i5];
    }
}

// ---- H12 precompute: H12[n][0:128] = nf[n]@W1[0:128]; H12[n][128:256] = nf[n]@W1[128:256]
// 32 nodes/block, 4 waves; wave w owns cols [64w, 64w+64).
__global__ __launch_bounds__(256)
void h12_kernel(const float* __restrict__ nf, const f16* __restrict__ Wcatf,
                f16* __restrict__ H12f)
{
    __shared__ f16 sa[32 * GSH];
    const int tid  = threadIdx.x;
    const int lane = tid & 63;
    const int w    = __builtin_amdgcn_readfirstlane(tid >> 6);
    const int c    = lane & 15;
    const int quad = lane >> 4;
    const int n0   = blockIdx.x * 32;

    {   // stage 32 node rows fp32 -> f16
        const int r = tid >> 3, q = tid & 7;
        const float* hrow = nf + (size_t)(n0 + r) * ND;
        #pragma unroll
        for (int i = 0; i < 4; ++i) {
            int ec = (q + 8 * i) * 4;
            float4 v = *(const float4*)(hrow + ec);
            f16x4 h; h[0] = (f16)v.x; h[1] = (f16)v.y; h[2] = (f16)v.z; h[3] = (f16)v.w;
            *(f16x4*)(sa + r * GSH + ec) = h;
        }
    }
    __syncthreads();

    f32x4 acc[2][4];
    #pragma unroll
    for (int mt = 0; mt < 2; ++mt)
        #pragma unroll
        for (int nt = 0; nt < 4; ++nt) acc[mt][nt] = (f32x4){0.f, 0.f, 0.f, 0.f};

    #pragma unroll
    for (int ks = 0; ks < 4; ++ks) {
        f16x8 fa[2];
        #pragma unroll
        for (int mt = 0; mt < 2; ++mt)
            fa[mt] = *(const f16x8*)(sa + (16 * mt + c) * GSH + ks * 32 + quad * 8);
        #pragma unroll
        for (int nt = 0; nt < 4; ++nt) {
            f16x8 b = *(const f16x8*)(Wcatf + (64 * w + nt * 16 + c) * 128 + ks * 32 + quad * 8);
            #pragma unroll
            for (int mt = 0; mt < 2; ++mt)
                acc[mt][nt] = __builtin_amdgcn_mfma_f32_16x16x32_f16(fa[mt], b, acc[mt][nt], 0, 0, 0);
        }
    }

    #pragma unroll
    for (int nt = 0; nt < 4; ++nt) {
        int col = 64 * w + nt * 16 + c;
        #pragma unroll
        for (int mt = 0; mt < 2; ++mt)
            #pragma unroll
            for (int r = 0; r < 4; ++r) {
                int row = 16 * mt + 4 * quad + r;
                H12f[(size_t)(n0 + row) * 256 + col] = (f16)acc[mt][nt][r];
            }
    }
}

// ---- CSR-style dst-sort: histogram -> scan -> scatter-rank ----
__global__ void hist_kernel(const int* __restrict__ eidx, int* __restrict__ cnt, int E) {
    int i = blockIdx.x * 256 + threadIdx.x;
    if (i < E) atomicAdd(&cnt[eidx[E + i]], 1);
}

__global__ __launch_bounds__(1024)
void scan_kernel(const int* __restrict__ cnt, int* __restrict__ woff, int N) {
    __shared__ int part[1024];
    const int t = threadIdx.x;
    const int CH = 40;
    int base = t * CH;
    int s = 0;
    for (int i = 0; i < CH; ++i) { int idx = base + i; if (idx < N) s += cnt[idx]; }
    part[t] = s;
    __syncthreads();
    for (int d = 1; d < 1024; d <<= 1) {
        int v = (t >= d) ? part[t - d] : 0;
        __syncthreads();
        part[t] += v;
        __syncthreads();
    }
    int run = (t == 0) ? 0 : part[t - 1];
    for (int i = 0; i < CH; ++i) {
        int idx = base + i;
        if (idx < N) { woff[idx] = run; run += cnt[idx]; }
    }
}

__global__ void scatter_kernel(const int* __restrict__ eidx, int* __restrict__ woff,
                               int* __restrict__ perm, int E) {
    int i = blockIdx.x * 256 + threadIdx.x;
    if (i < E) {
        int p = atomicAdd(&woff[eidx[E + i]], 1);
        perm[p] = i;
    }
}

// ---------------- edge message kernel (f16 MFMA, N-partitioned waves) ----------------
// 256 thr = 4 waves; 64 dst-sorted edges/block; 36.9 KB LDS -> 4 blocks/CU.
// GEMM1 reduced to K=64 (ef part); src/dst contributions gathered from H12f and
// added before LayerNorm. All LDS tiles XOR-swizzled -> ~conflict-free.
__global__ __launch_bounds__(256, 4)
void edge_kernel(const f16* __restrict__ H12f, const int* __restrict__ eidx,
                 const float* __restrict__ ef, const int* __restrict__ perm,
                 const f16* __restrict__ W1ef, const float* __restrict__ b1,
                 const float* __restrict__ ln_g, const float* __restrict__ ln_b,
                 const f16* __restrict__ W2f, const float* __restrict__ b2,
                 const float* __restrict__ gate_w, const float* __restrict__ gate_b,
                 float* __restrict__ agg, int E)
{
    // union tile, 32 KB:
    //   bytes [0,16384):      sh  [64 rows x 128 halves] swz16  (h12 sum, then h')
    //   bytes [16384,24576):  sef [64 rows x 64 halves]  swz16  (ef tile)
    //   after B5: whole 32 KB = smsg [64 rows x 128 fp32] swz4  (gated messages)
    __shared__ float smsg[TE * 128];
    __shared__ float sred[TE * 8];        // LN partials [row][w*2 + {p1,p2}]
    __shared__ float spart[TE][4];        // gate partials
    __shared__ float sg[TE];              // per-edge gate
    __shared__ int   se_s[TE], ssrc_s[TE], sdst_s[TE];

    char* shb  = (char*)smsg;             // sh base
    char* sefb = (char*)smsg + 16384;     // sef base

    const int tid  = threadIdx.x;
    const int lane = tid & 63;
    const int w    = __builtin_amdgcn_readfirstlane(tid >> 6);
    const int cb   = 32 * w;              // column base for this wave
    const int c    = lane & 15;
    const int quad = lane >> 4;
    const int e0   = blockIdx.x * TE;

    if (tid < TE) {
        int e = perm[e0 + tid];
        se_s[tid]   = e;
        ssrc_s[tid] = eidx[e];
        sdst_s[tid] = eidx[E + e];
    }
    __syncthreads();   // B0

    // ---- stage: h12 = H12f[src][0:128] + H12f[dst][128:256] (f16), ef tile, gate partials ----
    {
        const int r = tid >> 2, q = tid & 3;     // 4 threads per row
        const f16* h1p = H12f + (size_t)ssrc_s[r] * 256;
        const f16* h2p = H12f + (size_t)sdst_s[r] * 256 + 128;
        const int swz = (r & 7) << 4;
        #pragma unroll
        for (int i = 0; i < 4; ++i) {            // 4 chunks of 8 halves -> sh
            int ch = q + 4 * i;
            f16x8 a = *(const f16x8*)(h1p + ch * 8);
            f16x8 b = *(const f16x8*)(h2p + ch * 8);
            f16x8 s = a + b;
            *(f16x8*)(shb + ((r * 256 + ch * 16) ^ swz)) = s;
        }
        const float* erow = ef + (size_t)se_s[r] * ED;
        float gp = 0.f;
        #pragma unroll
        for (int j = 0; j < 2; ++j) {            // 2 chunks of 8 floats -> sef (f16)
            int ch = 2 * q + j;
            const float* p = erow + ch * 8;
            float4 v0 = *(const float4*)p;
            float4 v1 = *(const float4*)(p + 4);
            f16x8 h;
            h[0] = (f16)v0.x; h[1] = (f16)v0.y; h[2] = (f16)v0.z; h[3] = (f16)v0.w;
            h[4] = (f16)v1.x; h[5] = (f16)v1.y; h[6] = (f16)v1.z; h[7] = (f16)v1.w;
            *(f16x8*)(sefb + ((r * 128 + ch * 16) ^ swz)) = h;
            const float* gw = gate_w + ch * 8;
            gp = fmaf(v0.x, gw[0], gp); gp = fmaf(v0.y, gw[1], gp);
            gp = fmaf(v0.z, gw[2], gp); gp = fmaf(v0.w, gw[3], gp);
            gp = fmaf(v1.x, gw[4], gp); gp = fmaf(v1.y, gw[5], gp);
            gp = fmaf(v1.z, gw[6], gp); gp = fmaf(v1.w, gw[7], gp);
        }
        spart[r][q] = gp;
    }
    __syncthreads();   // B1

    if (tid < TE)      // sg consumed after B5; intervening barriers give visibility
        sg[tid] = sigmoidf_(spart[tid][0] + spart[tid][1] + spart[tid][2] + spart[tid][3] + gate_b[0]);

    // ---- GEMM1e: [64x64] (ef) @ [64x(32 cols/wave)] ----
    f32x4 acc[4][2];
    #pragma unroll
    for (int mt = 0; mt < 4; ++mt)
        #pragma unroll
        for (int nt = 0; nt < 2; ++nt) acc[mt][nt] = (f32x4){0.f, 0.f, 0.f, 0.f};

    #pragma unroll
    for (int ks = 0; ks < 2; ++ks) {
        f16x8 b0 = *(const f16x8*)(W1ef + (cb + c) * 64 + ks * 32 + quad * 8);
        f16x8 b1v = *(const f16x8*)(W1ef + (cb + 16 + c) * 64 + ks * 32 + quad * 8);
        #pragma unroll
        for (int mt = 0; mt < 4; ++mt) {
            f16x8 a = *(const f16x8*)(sefb + (((16 * mt + c) * 128 + ks * 64 + quad * 16) ^ ((c & 7) << 4)));
            acc[mt][0] = __builtin_amdgcn_mfma_f32_16x16x32_f16(a, b0,  acc[mt][0], 0, 0, 0);
            acc[mt][1] = __builtin_amdgcn_mfma_f32_16x16x32_f16(a, b1v, acc[mt][1], 0, 0, 0);
        }
    }

    // ---- bias + h12 add + LN partials over this wave's 32 cols ----
    float b1c[2], gvc[2], bvc[2], b2c[2];
    #pragma unroll
    for (int nt = 0; nt < 2; ++nt) {
        int col = cb + nt * 16 + c;
        b1c[nt] = b1[col]; gvc[nt] = ln_g[col]; bvc[nt] = ln_b[col]; b2c[nt] = b2[col];
    }
    #pragma unroll
    for (int mt = 0; mt < 4; ++mt) {
        float p1[4] = {0, 0, 0, 0}, p2[4] = {0, 0, 0, 0};
        #pragma unroll
        for (int nt = 0; nt < 2; ++nt)
            #pragma unroll
            for (int r = 0; r < 4; ++r) {
                int row = 16 * mt + 4 * quad + r;
                int col = cb + nt * 16 + c;
                float h12v = (float)(*(const f16*)(shb + ((row * 256 + col * 2) ^ ((row & 7) << 4))));
                float vv = acc[mt][nt][r] + b1c[nt] + h12v;
                acc[mt][nt][r] = vv;
                p1[r] += vv; p2[r] += vv * vv;
            }
        #pragma unroll
        for (int m = 1; m < 16; m <<= 1)
            #pragma unroll
            for (int r = 0; r < 4; ++r) {
                p1[r] += __shfl_xor(p1[r], m);
                p2[r] += __shfl_xor(p2[r], m);
            }
        if (c == 0) {
            #pragma unroll
            for (int r = 0; r < 4; ++r) {
                int row = 16 * mt + 4 * quad + r;
                sred[row * 8 + 2 * w + 0] = p1[r];
                sred[row * 8 + 2 * w + 1] = p2[r];
            }
        }
    }
    __syncthreads();   // B3  (also orders h12 reads before h' writes below)

    // ---- LN finalize + ReLU; h' (f16) into sh ----
    #pragma unroll
    for (int mt = 0; mt < 4; ++mt)
        #pragma unroll
        for (int r = 0; r < 4; ++r) {
            int row = 16 * mt + 4 * quad + r;
            f32x4 lo = *(const f32x4*)(sred + row * 8);
            f32x4 hi = *(const f32x4*)(sred + row * 8 + 4);
            float t1 = lo[0] + lo[2] + hi[0] + hi[2];
            float t2 = lo[1] + lo[3] + hi[1] + hi[3];
            float mu = t1 * (1.f / 128.f);
            float var = t2 * (1.f / 128.f) - mu * mu;
            float rs = rsqrtf(var + LN_EPS);
            #pragma unroll
            for (int nt = 0; nt < 2; ++nt) {
                int col = cb + nt * 16 + c;
                float vv = (acc[mt][nt][r] - mu) * rs * gvc[nt] + bvc[nt];
                vv = vv > 0.f ? vv : 0.f;
                *(f16*)(shb + ((row * 256 + col * 2) ^ ((row & 7) << 4))) = (f16)vv;
            }
        }
    __syncthreads();   // B4

    // ---- GEMM2: [64x128] @ [128x(32 cols/wave)] ----
    f32x4 acc2[4][2];
    #pragma unroll
    for (int mt = 0; mt < 4; ++mt)
        #pragma unroll
        for (int nt = 0; nt < 2; ++nt) acc2[mt][nt] = (f32x4){0.f, 0.f, 0.f, 0.f};
    #pragma unroll
    for (int ks = 0; ks < 4; ++ks) {
        f16x8 b0 = *(const f16x8*)(W2f + (cb + c) * 128 + ks * 32 + quad * 8);
        f16x8 b1v = *(const f16x8*)(W2f + (cb + 16 + c) * 128 + ks * 32 + quad * 8);
        #pragma unroll
        for (int mt = 0; mt < 4; ++mt) {
            f16x8 a = *(const f16x8*)(shb + (((16 * mt + c) * 256 + ks * 64 + quad * 16) ^ ((c & 7) << 4)));
            acc2[mt][0] = __builtin_amdgcn_mfma_f32_16x16x32_f16(a, b0,  acc2[mt][0], 0, 0, 0);
            acc2[mt][1] = __builtin_amdgcn_mfma_f32_16x16x32_f16(a, b1v, acc2[mt][1], 0, 0, 0);
        }
    }
    __syncthreads();   // B5: all sh reads done -> safe to overwrite union tile with fp32 messages

    // ---- gated messages (fp32) into LDS, swz4 on dwords ----
    #pragma unroll
    for (int mt = 0; mt < 4; ++mt)
        #pragma unroll
        for (int r = 0; r < 4; ++r) {
            int row = 16 * mt + 4 * quad + r;
            float gr = sg[row];
            #pragma unroll
            for (int nt = 0; nt < 2; ++nt) {
                int col = cb + nt * 16 + c;
                smsg[(row * 128 + col) ^ ((row & 7) << 2)] = (acc2[mt][nt][r] + b2c[nt]) * gr;
            }
        }
    __syncthreads();   // B6

    // ---- segment reduction over sorted dst: wave w walks rows [16w,16w+16), 2 cols/lane ----
    {
        const int rbase = 16 * w;
        int row0 = rbase;
        float run0 = smsg[(row0 * 128 + lane) ^ ((row0 & 7) << 2)];
        float run1 = smsg[(row0 * 128 + 64 + lane) ^ ((row0 & 7) << 2)];
        int prev = sdst_s[rbase];
        #pragma unroll
        for (int r = 1; r < 16; ++r) {
            int row = rbase + r;
            int d = sdst_s[row];               // wave-uniform broadcast
            float v0 = smsg[(row * 128 + lane) ^ ((row & 7) << 2)];
            float v1 = smsg[(row * 128 + 64 + lane) ^ ((row & 7) << 2)];
            if (d == prev) { run0 += v0; run1 += v1; }
            else {
                atomicAdd(agg + (size_t)prev * ND + lane,      run0);
                atomicAdd(agg + (size_t)prev * ND + 64 + lane, run1);
                run0 = v0; run1 = v1; prev = d;
            }
        }
        atomicAdd(agg + (size_t)prev * ND + lane,      run0);
        atomicAdd(agg + (size_t)prev * ND + 64 + lane, run1);
    }
}

// ---------------- GRU kernel (f16 MFMA) ----------------
// 256 thr = 4 waves; 32 nodes/block. Wave w owns gate-cols [32w,32w+32).
__global__ __launch_bounds__(256, 2)
void gru_kernel(const float* __restrict__ agg, const float* __restrict__ nf,
                const f16* __restrict__ Wihf, const float* __restrict__ b_ih,
                const f16* __restrict__ Whhf, const float* __restrict__ b_hh,
                float* __restrict__ out)
{
    __shared__ f16   sa[32 * GSH];
    __shared__ f16   sh[32 * GSH];
    __shared__ float shf[32 * GSF];   // fp32 h_prev for the z*h term

    const int tid  = threadIdx.x;
    const int lane = tid & 63;
    const int w    = __builtin_amdgcn_readfirstlane(tid >> 6);
    const int c    = lane & 15;
    const int quad = lane >> 4;
    const int n0   = blockIdx.x * 32;

    {
        const int r = tid >> 3, q = tid & 7;
        const float* arow = agg + (size_t)(n0 + r) * ND;
        const float* hrow = nf  + (size_t)(n0 + r) * ND;
        #pragma unroll
        for (int i = 0; i < 4; ++i) {
            int ec = (q + 8 * i) * 4;
            float4 va = *(const float4*)(arow + ec);
            f16x4 ha; ha[0] = (f16)va.x; ha[1] = (f16)va.y; ha[2] = (f16)va.z; ha[3] = (f16)va.w;
            *(f16x4*)(sa + r * GSH + ec) = ha;
            float4 vh = *(const float4*)(hrow + ec);
            f16x4 hh; hh[0] = (f16)vh.x; hh[1] = (f16)vh.y; hh[2] = (f16)vh.z; hh[3] = (f16)vh.w;
            *(f16x4*)(sh + r * GSH + ec) = hh;
            *(float4*)(shf + r * GSF + ec) = vh;
        }
    }
    __syncthreads();

    f32x4 aI[2][6], aH[2][6];   // [mt][gg*2+nt]
    #pragma unroll
    for (int mt = 0; mt < 2; ++mt)
        #pragma unroll
        for (int j = 0; j < 6; ++j) {
            aI[mt][j] = (f32x4){0.f, 0.f, 0.f, 0.f};
            aH[mt][j] = (f32x4){0.f, 0.f, 0.f, 0.f};
        }

    #pragma unroll
    for (int ks = 0; ks < 4; ++ks) {
        f16x8 fa[2], fh[2];
        #pragma unroll
        for (int mt = 0; mt < 2; ++mt) {
            fa[mt] = *(const f16x8*)(sa + (16 * mt + c) * GSH + ks * 32 + quad * 8);
            fh[mt] = *(const f16x8*)(sh + (16 * mt + c) * GSH + ks * 32 + quad * 8);
        }
        #pragma unroll
        for (int gg = 0; gg < 3; ++gg)
            #pragma unroll
            for (int nt = 0; nt < 2; ++nt) {
                int coln = gg * 128 + 32 * w + nt * 16 + c;
                f16x8 bI = *(const f16x8*)(Wihf + coln * 128 + ks * 32 + quad * 8);
                f16x8 bH = *(const f16x8*)(Whhf + coln * 128 + ks * 32 + quad * 8);
                #pragma unroll
                for (int mt = 0; mt < 2; ++mt) {
                    int j = gg * 2 + nt;
                    aI[mt][j] = __builtin_amdgcn_mfma_f32_16x16x32_f16(fa[mt], bI, aI[mt][j], 0, 0, 0);
                    aH[mt][j] = __builtin_amdgcn_mfma_f32_16x16x32_f16(fh[mt], bH, aH[mt][j], 0, 0, 0);
                }
            }
    }

    #pragma unroll
    for (int nt = 0; nt < 2; ++nt) {
        int col = 32 * w + nt * 16 + c;
        float bir = b_ih[col], biz = b_ih[128 + col], bin = b_ih[256 + col];
        float bhr = b_hh[col], bhz = b_hh[128 + col], bhn = b_hh[256 + col];
        #pragma unroll
        for (int mt = 0; mt < 2; ++mt)
            #pragma unroll
            for (int r = 0; r < 4; ++r) {
                int row = 16 * mt + 4 * quad + r;
                float rr = sigmoidf_(aI[mt][0 + nt][r] + bir + aH[mt][0 + nt][r] + bhr);
                float zz = sigmoidf_(aI[mt][2 + nt][r] + biz + aH[mt][2 + nt][r] + bhz);
                float nn = tanhf(aI[mt][4 + nt][r] + bin + rr * (aH[mt][4 + nt][r] + bhn));
                float hp = shf[row * GSF + col];
                out[(size_t)(n0 + row) * ND + col] = (1.f - zz) * nn + zz * hp;
            }
    }
}

extern "C" void kernel_launch(void* const* d_in, const int* in_sizes, int n_in,
                              void* d_out, int out_size, void* d_ws, size_t ws_size,
                              hipStream_t stream) {
    const float* nf     = (const float*)d_in[0];
    const int*   eidx   = (const int*)  d_in[1];
    const float* ef     = (const float*)d_in[2];
    const float* W1     = (const float*)d_in[3];
    const float* b1     = (const float*)d_in[4];
    const float* ln_g   = (const float*)d_in[5];
    const float* ln_b   = (const float*)d_in[6];
    const float* W2     = (const float*)d_in[7];
    const float* b2     = (const float*)d_in[8];
    const float* gate_w = (const float*)d_in[9];
    const float* gate_b = (const float*)d_in[10];
    const float* W_ih   = (const float*)d_in[11];
    const float* b_ih   = (const float*)d_in[12];
    const float* W_hh   = (const float*)d_in[13];
    const float* b_hh   = (const float*)d_in[14];
    float* out = (float*)d_out;

    const int N = in_sizes[0] / ND;   // 40000
    const int E = in_sizes[1] / 2;    // 640000

    char* ws = (char*)d_ws;
    float* agg  = (float*)ws;         ws += (size_t)N * ND * 4;     // 20.48 MB
    f16* H12f   = (f16*)ws;           ws += (size_t)N * 256 * 2;    // 20.48 MB
    f16* Wcatf  = (f16*)ws;           ws += 32768 * 2;
    f16* W1ef   = (f16*)ws;           ws += 8192 * 2;
    f16* W2f    = (f16*)ws;           ws += 16384 * 2;
    f16* Wihf   = (f16*)ws;           ws += 49152 * 2;
    f16* Whhf   = (f16*)ws;           ws += 49152 * 2;
    int* cnt    = (int*)ws;           ws += 40960 * 4;
    int* woff   = (int*)ws;           ws += 40960 * 4;
    int* perm   = (int*)ws;           ws += (size_t)E * 4;          // 2.56 MB

    hipMemsetAsync(agg, 0, (size_t)N * ND * 4, stream);
    hipMemsetAsync(cnt, 0, (size_t)N * 4, stream);
    convert_kernel<<<608, 256, 0, stream>>>(W1, W2, W_ih, W_hh,
                                            Wcatf, W1ef, W2f, Wihf, Whhf);
    h12_kernel<<<N / 32, 256, 0, stream>>>(nf, Wcatf, H12f);
    hist_kernel<<<(E + 255) / 256, 256, 0, stream>>>(eidx, cnt, E);
    scan_kernel<<<1, 1024, 0, stream>>>(cnt, woff, N);
    scatter_kernel<<<(E + 255) / 256, 256, 0, stream>>>(eidx, woff, perm, E);
    edge_kernel<<<E / TE, 256, 0, stream>>>(H12f, eidx, ef, perm, W1ef, b1, ln_g, ln_b,
                                            W2f, b2, gate_w, gate_b, agg, E);
    gru_kernel<<<N / 32, 256, 0, stream>>>(agg, nf, Wihf, b_ih, Whhf, b_hh, out);
}